// Round 14
// baseline (164.198 us; speedup 1.0000x reference)
//
#include <hip/hip_runtime.h>
#include <hip/hip_bf16.h>
#include <math.h>

typedef __bf16 bf16_t;
typedef __bf16 bf16x4 __attribute__((ext_vector_type(4)));
typedef __bf16 bf16x8 __attribute__((ext_vector_type(8)));
typedef float  f32x4  __attribute__((ext_vector_type(4)));

static constexpr int S_LEN = 4096;
static constexpr int D_DIM = 64;
static constexpr int H_NUM = 16;
static constexpr int BT    = 64;
static constexpr float QSCALE = 0.18033688011112042f;  // (1/sqrt(64)) * log2(e)
static constexpr float MB2    = 12.0f;  // fixed softmax shift (base-2)

__device__ __forceinline__ float fexp2(float x) {
#if __has_builtin(__builtin_amdgcn_exp2f)
  return __builtin_amdgcn_exp2f(x);   // raw v_exp_f32 (r10/r13-proven)
#else
  return exp2f(x);
#endif
}

// ---- prepack: VERBATIM r13 (HW-proven).
// K[h][d][s] f32 -> ktr[h][s][d] bf16 ; V[h][s][d] f32 -> vp[h][d][t'] bf16,
// t' = kt*32 + quad*8 + j  <->  t = kt*32 + (j>>2)*16 + quad*4 + (j&3).
__global__ __launch_bounds__(256)
void prepack(const float* __restrict__ kg, const float* __restrict__ vg,
             bf16_t* __restrict__ ktr, bf16_t* __restrict__ vpp) {
  __shared__ bf16_t tk[64][72];   // K^T tile [s][d]
  __shared__ bf16_t tv[64][72];   // V tile   [t][d]
  const int tid = threadIdx.x;
  const int h = blockIdx.x >> 6, sb = blockIdx.x & 63;
  const int s0 = sb * 64;
  const float* kh = kg + (size_t)h * D_DIM * S_LEN;
  const float* vh = vg + (size_t)h * S_LEN * D_DIM;

  #pragma unroll
  for (int it = 0; it < 4; ++it) {
    const int d = (tid >> 4) + it * 16;
    const int s = (tid & 15) * 4;
    const f32x4 x = *(const f32x4*)(kh + (size_t)d * S_LEN + s0 + s);  // K[d][s0+s..]
    #pragma unroll
    for (int i = 0; i < 4; ++i) tk[s + i][d] = (bf16_t)x[i];
    const f32x4 y = *(const f32x4*)(vh + (size_t)(s0 + d) * D_DIM + s); // V[s0+d][s..]
    bf16x4 yb;
    #pragma unroll
    for (int i = 0; i < 4; ++i) yb[i] = (bf16_t)y[i];
    *(bf16x4*)&tv[d][s] = yb;
  }
  __syncthreads();

  // K out: ktr[(h*S + s0+s)*64 + d]
  {
    const int s = tid >> 2, c = (tid & 3) * 16;
    const bf16x8 a = *(const bf16x8*)&tk[s][c];
    const bf16x8 b = *(const bf16x8*)&tk[s][c + 8];
    bf16_t* o = ktr + ((size_t)h * S_LEN + s0 + s) * D_DIM + c;
    *(bf16x8*)o = a;
    *(bf16x8*)(o + 8) = b;
  }
  // V out: vpp[(h*64 + d)*S + s0 + t'], permuted gather over tv columns
  {
    const int d = tid >> 2, g = (tid & 3) * 16;
    bf16x8 w0, w1;
    #pragma unroll
    for (int x = 0; x < 16; ++x) {
      const int tp = g + x;
      const int kt = tp >> 5, rem = tp & 31, qd = rem >> 3, j = rem & 7;
      const int t  = kt * 32 + (j >> 2) * 16 + qd * 4 + (j & 3);
      const bf16_t val = tv[t][d];
      if (x < 8) w0[x] = val; else w1[x - 8] = val;
    }
    bf16_t* o = vpp + ((size_t)h * D_DIM + d) * S_LEN + s0 + g;
    *(bf16x8*)o = w0;
    *(bf16x8*)(o + 8) = w1;
  }
}

// S^T flash attention, causal, fixed-max softmax. r13 dataflow verbatim;
// ONLY delta: ride-along scheduling. Block j pairs rt=1 = HEAVY 64-row tile
// (63-j) with rt=0 = LIGHT tile j (active only in early steps via act0 guard).
// Block length = 64-j in [33,64]; job order makes co-scheduled pairs
// (bx, bx+256) sum to a constant 97 steps -> ~2 blocks/CU resident for the
// whole makespan instead of decaying to 1.
__global__ __launch_bounds__(256, 2)
void attn_fwd(const float* __restrict__ qg, const bf16_t* __restrict__ ktr,
              const bf16_t* __restrict__ vpp, float* __restrict__ og) {
  __shared__ __align__(16) bf16_t kT[2][64][72];   // K^T tile [t][d]
  __shared__ __align__(16) bf16_t vT[2][64][72];   // V^T tile [d][t'] (permuted)

  const int tid  = threadIdx.x;
  const int wave = tid >> 6;
  const int lane = tid & 63;
  const int col  = lane & 15;
  const int quad = lane >> 4;

  // job decode: j = light tile index; pairs (jb, jb+16) give j + j' = 31
  // -> lengths (64-j) + (64-j') = 97 constant on each CU.
  const int h  = blockIdx.x & 15;
  const int jb = blockIdx.x >> 4;                        // 0..31
  const int j  = (jb < 16) ? (2 * jb) : (63 - 2 * jb);   // 0..31, bijective
  const int nsteps = 64 - j;                             // 33..64

  const float*  qh  = qg  + (size_t)h * S_LEN * D_DIM;
  const bf16_t* kth = ktr + (size_t)h * S_LEN * D_DIM;   // [s][d]
  const bf16_t* vph = vpp + (size_t)h * D_DIM * S_LEN;   // [d][t'_global]
  float*        oh  = og  + (size_t)h * S_LEN * D_DIM;

  const int base[2] = { j * 64 + wave * 16,              // rt=0: light rows
                        (63 - j) * 64 + wave * 16 };     // rt=1: heavy rows

  // staging mapping (r13-proven): thread copies 16 elems of one row
  const int st = tid >> 2;             // K: t-local 0..63 | V: d 0..63
  const int sc = (tid & 3) * 16;       // 0,16,32,48

  // ---- Q^T B-fragments (r13-proven form, per row-tile base) ----
  bf16x8 qb[2][2];
  #pragma unroll
  for (int rt = 0; rt < 2; ++rt) {
    const float* qp = qh + (size_t)(base[rt] + col) * D_DIM;
    #pragma unroll
    for (int kk = 0; kk < 2; ++kk) {
      f32x4 lo = *(const f32x4*)(qp + kk * 32 + quad * 8);
      f32x4 hi = *(const f32x4*)(qp + kk * 32 + quad * 8 + 4);
      #pragma unroll
      for (int jj = 0; jj < 4; ++jj) {
        qb[rt][kk][jj]     = (bf16_t)(lo[jj] * QSCALE);
        qb[rt][kk][jj + 4] = (bf16_t)(hi[jj] * QSCALE);
      }
    }
  }

  f32x4 acc[2][4];
  #pragma unroll
  for (int rt = 0; rt < 2; ++rt)
    #pragma unroll
    for (int nt = 0; nt < 4; ++nt) acc[rt][nt] = (f32x4){0.f, 0.f, 0.f, 0.f};
  float l_i[2] = {0.f, 0.f};

  // ---- prologue: stage tile 0 into buffer 0 (bf16 contiguous copy) ----
  {
    const bf16_t* kp = kth + (size_t)st * 64 + sc;
    const bf16_t* vs = vph + (size_t)st * S_LEN + sc;
    *(bf16x8*)&kT[0][st][sc]     = *(const bf16x8*)kp;
    *(bf16x8*)&kT[0][st][sc + 8] = *(const bf16x8*)(kp + 8);
    *(bf16x8*)&vT[0][st][sc]     = *(const bf16x8*)vs;
    *(bf16x8*)&vT[0][st][sc + 8] = *(const bf16x8*)(vs + 8);
  }
  __syncthreads();

  for (int s = 0; s < nsteps; ++s) {
    const int buf = s & 1;
    const int t0  = s * BT;
    const bool pf = (s + 1 < nsteps);
    const bool act0 = (t0 <= base[0] + 15);   // light tile still active?

    // ---- K fragments (r13-proven padded reads) ----
    bf16x8 kf[4][2];
    #pragma unroll
    for (int ct = 0; ct < 4; ++ct)
      #pragma unroll
      for (int kk = 0; kk < 2; ++kk)
        kf[ct][kk] = *(const bf16x8*)&kT[buf][ct * 16 + col][kk * 32 + quad * 8];

    // ---- QK^T -> S^T (C init -MB2) ----
    f32x4 sc_[2][4];
    #pragma unroll
    for (int rt = 0; rt < 2; ++rt)
      #pragma unroll
      for (int ct = 0; ct < 4; ++ct) sc_[rt][ct] = (f32x4){-MB2, -MB2, -MB2, -MB2};
    #pragma unroll
    for (int ct = 0; ct < 4; ++ct)
      #pragma unroll
      for (int kk = 0; kk < 2; ++kk) {
        if (act0)
          sc_[0][ct] = __builtin_amdgcn_mfma_f32_16x16x32_bf16(kf[ct][kk], qb[0][kk], sc_[0][ct], 0, 0, 0);
        sc_[1][ct] = __builtin_amdgcn_mfma_f32_16x16x32_bf16(kf[ct][kk], qb[1][kk], sc_[1][ct], 0, 0, 0);
      }

    // ---- K prefetch for next tile (bf16 contiguous) ----
    bf16x8 kp0, kp1;
    if (pf) {
      const bf16_t* kp = kth + (size_t)(t0 + BT + st) * 64 + sc;
      kp0 = *(const bf16x8*)kp;
      kp1 = *(const bf16x8*)(kp + 8);
    }

    // ---- fixed-max softmax -> PV B-fragments in registers (r13-proven) ----
    bf16x8 pfrag[2][2];
    #pragma unroll
    for (int rt = 0; rt < 2; ++rt) {
      if (rt == 0 && !act0) continue;
      const int qrow = base[rt] + col;
      if (t0 + BT - 1 > base[rt]) {   // diagonal step for this tile: mask
        #pragma unroll
        for (int ct = 0; ct < 4; ++ct)
          #pragma unroll
          for (int r = 0; r < 4; ++r)
            sc_[rt][ct][r] = (t0 + ct * 16 + quad * 4 + r > qrow) ? -1e30f : sc_[rt][ct][r];
      }
      float rs0 = 0.f, rs1 = 0.f;
      #pragma unroll
      for (int ct = 0; ct < 4; ++ct) {
        const float p0 = fexp2(sc_[rt][ct][0]);
        const float p1 = fexp2(sc_[rt][ct][1]);
        const float p2 = fexp2(sc_[rt][ct][2]);
        const float p3 = fexp2(sc_[rt][ct][3]);
        rs0 += p0 + p1; rs1 += p2 + p3;
        const int kt = ct >> 1, hh = (ct & 1) * 4;
        pfrag[rt][kt][hh + 0] = (bf16_t)p0;
        pfrag[rt][kt][hh + 1] = (bf16_t)p1;
        pfrag[rt][kt][hh + 2] = (bf16_t)p2;
        pfrag[rt][kt][hh + 3] = (bf16_t)p3;
      }
      l_i[rt] += rs0 + rs1;
    }

    // ---- stage prefetched K into buf^1 ----
    if (pf) {
      *(bf16x8*)&kT[buf ^ 1][st][sc]     = kp0;
      *(bf16x8*)&kT[buf ^ 1][st][sc + 8] = kp1;
    }

    // ---- V prefetch ----
    bf16x8 vp0, vp1;
    if (pf) {
      const bf16_t* vs = vph + (size_t)st * S_LEN + (t0 + BT) + sc;
      vp0 = *(const bf16x8*)vs;
      vp1 = *(const bf16x8*)(vs + 8);
    }

    // ---- PV -> O^T (A = V^T from LDS, B = pfrag registers) ----
    #pragma unroll
    for (int kt = 0; kt < 2; ++kt)
      #pragma unroll
      for (int nt = 0; nt < 4; ++nt) {
        const bf16x8 vf = *(const bf16x8*)&vT[buf][nt * 16 + col][kt * 32 + quad * 8];
        if (act0)
          acc[0][nt] = __builtin_amdgcn_mfma_f32_16x16x32_bf16(vf, pfrag[0][kt], acc[0][nt], 0, 0, 0);
        acc[1][nt] = __builtin_amdgcn_mfma_f32_16x16x32_bf16(vf, pfrag[1][kt], acc[1][nt], 0, 0, 0);
      }

    // ---- stage prefetched V into buf^1 ----
    if (pf) {
      *(bf16x8*)&vT[buf ^ 1][st][sc]     = vp0;
      *(bf16x8*)&vT[buf ^ 1][st][sc + 8] = vp1;
    }

    __syncthreads();   // the ONLY barrier per step
  }

  // ---- epilogue: reduce l across quads, normalize, store (r13-proven) ----
  #pragma unroll
  for (int rt = 0; rt < 2; ++rt) {
    float l = l_i[rt];
    l += __shfl_xor(l, 16);
    l += __shfl_xor(l, 32);
    const float inv_l = 1.0f / l;
    const int qr = base[rt] + col;
    float* op = oh + (size_t)qr * D_DIM + quad * 4;
    #pragma unroll
    for (int nt = 0; nt < 4; ++nt) {
      f32x4 o;
      o[0] = acc[rt][nt][0] * inv_l; o[1] = acc[rt][nt][1] * inv_l;
      o[2] = acc[rt][nt][2] * inv_l; o[3] = acc[rt][nt][3] * inv_l;
      *(f32x4*)(op + nt * 16) = o;
    }
  }
}

extern "C" void kernel_launch(void* const* d_in, const int* in_sizes, int n_in,
                              void* d_out, int out_size, void* d_ws, size_t ws_size,
                              hipStream_t stream) {
  const float* q = (const float*)d_in[0];
  const float* k = (const float*)d_in[1];
  const float* v = (const float*)d_in[2];
  float* out = (float*)d_out;

  // ws: [0,8M) ktr bf16 | [8M,16M) vp bf16 -> exactly 16 MB (proven budget)
  const size_t KB = (size_t)H_NUM * S_LEN * D_DIM * 2;   // 8,388,608
  bf16_t* ktr = (bf16_t*)d_ws;
  bf16_t* vp  = (bf16_t*)((char*)d_ws + KB);

  dim3 block(256);
  prepack<<<dim3(H_NUM * 64), block, 0, stream>>>(k, v, ktr, vp);
  attn_fwd<<<dim3(H_NUM * 32), block, 0, stream>>>(q, ktr, vp, out);
}